// Round 15
// baseline (299.613 us; speedup 1.0000x reference)
//
#include <hip/hip_runtime.h>

#define DM 1024
#define NH 16
#define HD 64
#define BB 2
#define SS 2048
#define MTOT (BB*SS)   // 4096 rows of x
#define NTOT (4*DM)    // 4096 projection outputs

typedef __attribute__((ext_vector_type(8))) short short8;  // 8 bf16 (4 VGPRs)
typedef __attribute__((ext_vector_type(4))) float f32x4;   // 4 f32

#define MFMA(a,b,c) __builtin_amdgcn_mfma_f32_16x16x32_bf16((a),(b),(c),0,0,0)

__device__ inline unsigned short f2bf(float f) {
  union { float f; unsigned u; } v; v.f = f;
  unsigned r = v.u + 0x7FFFu + ((v.u >> 16) & 1u);  // RNE
  return (unsigned short)(r >> 16);
}

__device__ inline void gload_lds16(const void* g, void* l) {
  void* gnc = const_cast<void*>(g);
  __builtin_amdgcn_global_load_lds(
      (__attribute__((address_space(1))) void*)gnc,
      (__attribute__((address_space(3))) void*)l, 16, 0, 0);
}

// ---------------- K0: f32 -> bf16 conversion (x and 4 weight mats) ----------
__global__ __launch_bounds__(256) void k_convert(
    const float* __restrict__ x, const float* __restrict__ w0,
    const float* __restrict__ w1, const float* __restrict__ w2,
    const float* __restrict__ w3,
    unsigned short* __restrict__ xb, unsigned short* __restrict__ wb) {
  const int T4 = (MTOT * DM) / 4;  // 1M float4 per buffer
  int stride = gridDim.x * blockDim.x;
  for (int i = blockIdx.x * blockDim.x + threadIdx.x; i < 2 * T4; i += stride) {
    const float* src; unsigned short* dst;
    if (i < T4) { src = x + (size_t)i * 4; dst = xb + (size_t)i * 4; }
    else {
      int flat = (i - T4) * 4;
      int sel = flat >> 20;
      int off = flat & ((1 << 20) - 1);
      const float* w = (sel == 0) ? w0 : (sel == 1) ? w1 : (sel == 2) ? w2 : w3;
      src = w + off; dst = wb + flat;
    }
    float4 v = *(const float4*)src;
    ushort4 o; o.x = f2bf(v.x); o.y = f2bf(v.y); o.z = f2bf(v.z); o.w = f2bf(v.w);
    *(ushort4*)dst = o;
  }
}

// ---------------- K1: fused projection GEMM [4096,1024]x[4096,1024]^T -------
__global__ __launch_bounds__(256) void k_proj(
    const unsigned short* __restrict__ xb, const unsigned short* __restrict__ wb,
    const float* __restrict__ bbd, const float* __restrict__ bq,
    const float* __restrict__ bk, const float* __restrict__ bv,
    const float* __restrict__ radial,
    float* __restrict__ outbd,
    unsigned short* __restrict__ qb, unsigned short* __restrict__ kb,
    unsigned short* __restrict__ vb) {
  __shared__ unsigned short lsA[128 * 64];
  __shared__ unsigned short lsB[128 * 64];
  const int tid = threadIdx.x;
  const int wave = tid >> 6, lane = tid & 63;
  const int wr = wave >> 1, wc = wave & 1;   // 2x2 wave grid, 64x64 per wave
  // bijective XCD swizzle: 1024 blocks % 8 == 0
  const int lin = blockIdx.y * gridDim.x + blockIdx.x;
  const int swz = (lin & 7) * 128 + (lin >> 3);
  const int m0 = (swz >> 5) * 128, n0 = (swz & 31) * 128;
  const int ro = lane & 15, gg = lane >> 4;
  const int srow = lane >> 3;        // 0..7 within an 8-row chunk
  const int scol = (lane & 7) * 8;   // bf16 col within 64
  f32x4 acc[4][4] = {};
  for (int kt = 0; kt < DM / 64; ++kt) {
    __syncthreads();
    #pragma unroll
    for (int i = 0; i < 4; ++i) {
      int c = wave * 4 + i;          // chunk 0..15, 8 rows each
      const unsigned short* ga = xb + (size_t)(m0 + c * 8 + srow) * DM + kt * 64 + scol;
      gload_lds16(ga, (void*)(lsA + c * 512));
      const unsigned short* gb = wb + (size_t)(n0 + c * 8 + srow) * DM + kt * 64 + scol;
      gload_lds16(gb, (void*)(lsB + c * 512));
    }
    __syncthreads();
    #pragma unroll
    for (int ks = 0; ks < 2; ++ks) {
      short8 a[4], b[4];
      int ko = ks * 32 + gg * 8;
      #pragma unroll
      for (int r = 0; r < 4; ++r)
        a[r] = *(const short8*)&lsA[(wr * 64 + r * 16 + ro) * 64 + ko];
      #pragma unroll
      for (int c = 0; c < 4; ++c)
        b[c] = *(const short8*)&lsB[(wc * 64 + c * 16 + ro) * 64 + ko];
      #pragma unroll
      for (int r = 0; r < 4; ++r)
        #pragma unroll
        for (int c = 0; c < 4; ++c)
          acc[r][c] = MFMA(a[r], b[c], acc[r][c]);
    }
  }
  const int which = n0 >> 10;  // uniform per block
  #pragma unroll
  for (int r = 0; r < 4; ++r) {
    const int mbase = m0 + wr * 64 + r * 16 + gg * 4;
    #pragma unroll
    for (int c = 0; c < 4; ++c) {
      const int n = n0 + wc * 64 + c * 16 + ro;
      const int nn = n & 1023;
      #pragma unroll
      for (int j = 0; j < 4; ++j) {
        const int m = mbase + j;
        float v = acc[r][c][j];
        if (which == 0) {
          outbd[(size_t)m * DM + nn] = v + bbd[nn];
        } else {
          const int h = nn >> 6, d = nn & 63;
          const int b2 = m >> 11, s = m & 2047;
          const size_t o = (((size_t)(b2 * NH + h)) * SS + s) * HD + d;
          if (which == 1) {
            float sg = 1.f / (1.f + __expf(-radial[h]));
            qb[o] = f2bf((v + bq[nn]) * sg);
          } else if (which == 2) {
            kb[o] = f2bf(v + bk[nn]);
          } else {
            vb[o] = f2bf(v + bv[nn]);
          }
        }
      }
    }
  }
}

// ---------------- K1b: transpose V -> vt[bh][64][2048] ----------------------
__global__ __launch_bounds__(256) void k_vt(
    const unsigned short* __restrict__ vb, unsigned short* __restrict__ vt) {
  __shared__ unsigned short t[64][65];
  const int bh = blockIdx.y, st = blockIdx.x;
  const int tid = threadIdx.x;
  const int r = tid >> 2, c4 = (tid & 3) * 16;
  const unsigned short* src = vb + ((size_t)bh * SS + st * 64 + r) * HD + c4;
  #pragma unroll
  for (int i = 0; i < 16; i += 4) {
    ushort4 v = *(const ushort4*)(src + i);
    t[r][c4 + i + 0] = v.x; t[r][c4 + i + 1] = v.y;
    t[r][c4 + i + 2] = v.z; t[r][c4 + i + 3] = v.w;
  }
  __syncthreads();
  const int dd = tid >> 2, s4 = (tid & 3) * 16;
  unsigned short* dst = vt + ((size_t)bh * HD + dd) * SS + st * 64 + s4;
  #pragma unroll
  for (int i = 0; i < 16; i += 4) {
    ushort4 o;
    o.x = t[s4 + i + 0][dd]; o.y = t[s4 + i + 1][dd];
    o.z = t[s4 + i + 2][dd]; o.w = t[s4 + i + 3][dd];
    *(ushort4*)(dst + i) = o;
  }
}

// ---------------- K2a: pass-1 as lean standalone kernel ---------------------
// Row sums of exp(s*fac). Grid split 2x along k-range (2048 blocks = 8/CU at
// 16KB LDS): partial sums to two planes (deterministic, no atomics).
__global__ __launch_bounds__(256) void k_sum(
    const unsigned short* __restrict__ qb, const unsigned short* __restrict__ kb,
    const float* __restrict__ tsc, float* __restrict__ sums) {
  __shared__ unsigned short lk[2][64 * 64];                  // 16 KB
  const int half = blockIdx.x >> 5, qt = blockIdx.x & 31, bh = blockIdx.y;
  const int tid = threadIdx.x, wave = tid >> 6, lane = tid & 63;
  const int ro = lane & 15, gg = lane >> 4;
  const unsigned short* kb_bh = kb + (size_t)bh * SS * HD;
  int sr0, sc0, sr1, sc1;
  {
    int s0 = (wave * 2 + 0) * 64 + lane;
    int s1 = (wave * 2 + 1) * 64 + lane;
    sr0 = s0 >> 3; sc0 = (s0 & 7) ^ (sr0 & 7);
    sr1 = s1 >> 3; sc1 = (s1 & 7) ^ (sr1 & 7);
  }
#define STAGE_K(buf, kt) do { \
    const unsigned short* g = kb_bh + (size_t)(kt) * 64 * HD; \
    gload_lds16(g + sr0 * 64 + sc0 * 8, (void*)(lk[buf] + (wave * 2 + 0) * 512)); \
    gload_lds16(g + sr1 * 64 + sc1 * 8, (void*)(lk[buf] + (wave * 2 + 1) * 512)); \
  } while (0)
  STAGE_K(0, half * 16);
  const unsigned short* qrow =
      qb + ((size_t)bh * SS + qt * 64 + wave * 16 + ro) * HD;
  short8 aq0 = *(const short8*)(qrow + gg * 8);
  short8 aq1 = *(const short8*)(qrow + 32 + gg * 8);
  const float fac = tsc[0] * 0.125f;
  __syncthreads();
  float psum = 0.f;
  int cur = 0;
  for (int i = 0; i < 16; ++i) {
    const int ct = half * 16 + i;
    if (i < 15) STAGE_K(cur ^ 1, ct + 1);
    const unsigned short* kbuf = lk[cur];
    #pragma unroll
    for (int sub = 0; sub < 4; ++sub) {
      const int rr = sub * 16 + ro;
      const unsigned short* kr = kbuf + rr * 64;
      short8 b0 = *(const short8*)&kr[(gg ^ (rr & 7)) * 8];
      short8 b1 = *(const short8*)&kr[((4 + gg) ^ (rr & 7)) * 8];
      f32x4 sf = {};
      sf = MFMA(b0, aq0, sf);
      sf = MFMA(b1, aq1, sf);
      psum += __expf(sf[0] * fac) + __expf(sf[1] * fac)
            + __expf(sf[2] * fac) + __expf(sf[3] * fac);
    }
    __syncthreads();
    cur ^= 1;
  }
  psum += __shfl_xor(psum, 16);
  psum += __shfl_xor(psum, 32);
  if (lane < 16)
    sums[(size_t)half * BB * NH * SS + (size_t)bh * SS + qt * 64 + wave * 16 + ro] = psum;
#undef STAGE_K
}

// ---------------- K2b: pass-2 only: recompute QK, attn write, PV ------------
// r10 structure minus pass 1; rsum read from the two partial-sum planes.
__global__ __launch_bounds__(256) void k_attn_pv(
    const unsigned short* __restrict__ qb, const unsigned short* __restrict__ kb,
    const unsigned short* __restrict__ vt, const float* __restrict__ tsc,
    const float* __restrict__ sums,
    float* __restrict__ attn, float* __restrict__ out) {
  __shared__ unsigned short lk[2][64 * 64];                  // 16 KB
  __shared__ unsigned short lv[2][64 * 64];                  // 16 KB
  __shared__ __align__(16) unsigned short pt[4][16 * 64];    // 8 KB
  const int bh = blockIdx.y, qt = blockIdx.x;
  const int tid = threadIdx.x, wave = tid >> 6, lane = tid & 63;
  const int ro = lane & 15, gg = lane >> 4;

  const unsigned short* kb_bh = kb + (size_t)bh * SS * HD;
  const unsigned short* vt_bh = vt + (size_t)bh * HD * SS;

  int sr0, sc0, sr1, sc1;
  {
    int s0 = (wave * 2 + 0) * 64 + lane;
    int s1 = (wave * 2 + 1) * 64 + lane;
    sr0 = s0 >> 3; sc0 = (s0 & 7) ^ (sr0 & 7);
    sr1 = s1 >> 3; sc1 = (s1 & 7) ^ (sr1 & 7);
  }

#define STAGE_K(buf, kt) do { \
    const unsigned short* g = kb_bh + (size_t)(kt) * 64 * HD; \
    gload_lds16(g + sr0 * 64 + sc0 * 8, (void*)(lk[buf] + (wave * 2 + 0) * 512)); \
    gload_lds16(g + sr1 * 64 + sc1 * 8, (void*)(lk[buf] + (wave * 2 + 1) * 512)); \
  } while (0)
#define STAGE_V(buf, kt) do { \
    const unsigned short* g = vt_bh + (size_t)(kt) * 64; \
    gload_lds16(g + (size_t)sr0 * SS + sc0 * 8, (void*)(lv[buf] + (wave * 2 + 0) * 512)); \
    gload_lds16(g + (size_t)sr1 * SS + sc1 * 8, (void*)(lv[buf] + (wave * 2 + 1) * 512)); \
  } while (0)

  STAGE_K(0, 0);
  STAGE_V(0, 0);

  const int row = qt * 64 + wave * 16 + ro;
  const unsigned short* qrow = qb + ((size_t)bh * SS + row) * HD;
  short8 aq0 = *(const short8*)(qrow + gg * 8);
  short8 aq1 = *(const short8*)(qrow + 32 + gg * 8);
  const float fac = tsc[0] * 0.125f;
  const float p0 = sums[(size_t)bh * SS + row];
  const float p1 = sums[(size_t)BB * NH * SS + (size_t)bh * SS + row];
  const float rsum = 1.f / (p0 + p1 + 1e-8f);

  __syncthreads();  // drains stage(0) + Q/rsum loads

  float* ab = attn + ((size_t)bh * SS + row) * SS;
  unsigned short* pw = &pt[wave][0];
  f32x4 acc[4] = {};
  int cur = 0;
  for (int ct = 0; ct < 32; ++ct) {
    asm volatile("s_waitcnt vmcnt(4)" ::: "memory");
    __builtin_amdgcn_s_barrier();
    if (ct < 31) { STAGE_K(cur ^ 1, ct + 1); STAGE_V(cur ^ 1, ct + 1); }
    const unsigned short* kbuf = lk[cur];
    const unsigned short* vbuf = lv[cur];
    f32x4 st[4];
    #pragma unroll
    for (int sub = 0; sub < 4; ++sub) {
      const int rr = sub * 16 + ro;
      const unsigned short* kr = kbuf + rr * 64;
      short8 b0 = *(const short8*)&kr[(gg ^ (rr & 7)) * 8];
      short8 b1 = *(const short8*)&kr[((4 + gg) ^ (rr & 7)) * 8];
      f32x4 sf = {};
      sf = MFMA(b0, aq0, sf);
      sf = MFMA(b1, aq1, sf);
      st[sub][0] = __expf(sf[0] * fac) * rsum;
      st[sub][1] = __expf(sf[1] * fac) * rsum;
      st[sub][2] = __expf(sf[2] * fac) * rsum;
      st[sub][3] = __expf(sf[3] * fac) * rsum;
    }
    #pragma unroll
    for (int sub = 0; sub < 4; ++sub)
      __builtin_nontemporal_store(st[sub],
          (f32x4*)(ab + (ct * 4 + sub) * 16 + gg * 4));
    #pragma unroll
    for (int sub = 0; sub < 4; ++sub) {
      unsigned w0, w1;
      asm("v_cvt_pk_bf16_f32 %0, %1, %2" : "=v"(w0) : "v"(st[sub][0]), "v"(st[sub][1]));
      asm("v_cvt_pk_bf16_f32 %0, %1, %2" : "=v"(w1) : "v"(st[sub][2]), "v"(st[sub][3]));
      const int slot = (sub * 2 + (gg >> 1)) ^ (ro & 7);
      *(uint2*)((char*)pw + ro * 128 + slot * 16 + (gg & 1) * 8) = make_uint2(w0, w1);
    }
    #pragma unroll
    for (int ks = 0; ks < 2; ++ks) {
      const int pslot = (ks * 4 + gg) ^ (ro & 7);
      short8 pa = *(const short8*)((const char*)pw + ro * 128 + pslot * 16);
      #pragma unroll
      for (int dc = 0; dc < 4; ++dc) {
        const int rr = dc * 16 + ro;
        const int cc = (ks * 4 + gg) ^ (rr & 7);
        short8 bvf = *(const short8*)&vbuf[rr * 64 + cc * 8];
        acc[dc] = MFMA(pa, bvf, acc[dc]);
      }
    }
    cur ^= 1;
  }

  // epilogue: out += PV (boundary already written by k_proj)
  const int b2 = bh >> 4, h = bh & 15;
  const int s0 = qt * 64 + wave * 16 + gg * 4;
  #pragma unroll
  for (int dc = 0; dc < 4; ++dc)
    #pragma unroll
    for (int j = 0; j < 4; ++j) {
      size_t o = ((size_t)b2 * SS + s0 + j) * DM + h * HD + dc * 16 + ro;
      out[o] += acc[dc][j];
    }
#undef STAGE_K
#undef STAGE_V
}

extern "C" void kernel_launch(void* const* d_in, const int* in_sizes, int n_in,
                              void* d_out, int out_size, void* d_ws, size_t ws_size,
                              hipStream_t stream) {
  (void)in_sizes; (void)n_in; (void)out_size; (void)ws_size;
  const float* x   = (const float*)d_in[0];
  const float* Wb  = (const float*)d_in[1];
  const float* bb  = (const float*)d_in[2];
  const float* Wq  = (const float*)d_in[3];
  const float* bq  = (const float*)d_in[4];
  const float* Wk  = (const float*)d_in[5];
  const float* bk  = (const float*)d_in[6];
  const float* Wv  = (const float*)d_in[7];
  const float* bv  = (const float*)d_in[8];
  const float* rad = (const float*)d_in[9];
  const float* tsc = (const float*)d_in[10];

  float* out  = (float*)d_out;
  float* attn = out + (size_t)MTOT * DM;  // second output, also early scratch

  // ws: qb(8MB) kb(8MB) vt(8MB) sums(512KB)
  unsigned short* qb = (unsigned short*)d_ws;
  unsigned short* kb = qb + (size_t)4 * 1024 * 1024;
  unsigned short* vt = kb + (size_t)4 * 1024 * 1024;
  float* sums = (float*)(vt + (size_t)4 * 1024 * 1024);  // 2 planes x 64K f32

  // scratch carved from the attn output region (overwritten later by k_attn_pv)
  unsigned short* xb = (unsigned short*)attn;
  unsigned short* wb = xb + (size_t)4 * 1024 * 1024;
  unsigned short* vb = wb + (size_t)4 * 1024 * 1024;

  k_convert<<<2048, 256, 0, stream>>>(x, Wb, Wq, Wk, Wv, xb, wb);
  k_proj<<<dim3(32, 32), 256, 0, stream>>>(xb, wb, bb, bq, bk, bv, rad, out, qb, kb, vb);
  k_vt<<<dim3(32, 32), 256, 0, stream>>>(vb, vt);
  k_sum<<<dim3(64, 32), 256, 0, stream>>>(qb, kb, tsc, sums);
  k_attn_pv<<<dim3(32, 32), 256, 0, stream>>>(qb, kb, vt, tsc, sums, attn, out);
}

// Round 16
// 269.535 us; speedup vs baseline: 1.1116x; 1.1116x over previous
//
#include <hip/hip_runtime.h>

#define DM 1024
#define NH 16
#define HD 64
#define BB 2
#define SS 2048
#define MTOT (BB*SS)   // 4096 rows of x
#define NTOT (4*DM)    // 4096 projection outputs

typedef __attribute__((ext_vector_type(8))) short short8;  // 8 bf16 (4 VGPRs)
typedef __attribute__((ext_vector_type(4))) float f32x4;   // 4 f32

#define MFMA(a,b,c) __builtin_amdgcn_mfma_f32_16x16x32_bf16((a),(b),(c),0,0,0)

__device__ inline unsigned short f2bf(float f) {
  union { float f; unsigned u; } v; v.f = f;
  unsigned r = v.u + 0x7FFFu + ((v.u >> 16) & 1u);  // RNE
  return (unsigned short)(r >> 16);
}

__device__ inline void gload_lds16(const void* g, void* l) {
  void* gnc = const_cast<void*>(g);
  __builtin_amdgcn_global_load_lds(
      (__attribute__((address_space(1))) void*)gnc,
      (__attribute__((address_space(3))) void*)l, 16, 0, 0);
}

// ---------------- K0: f32 -> bf16 conversion (x and 4 weight mats) ----------
__global__ __launch_bounds__(256) void k_convert(
    const float* __restrict__ x, const float* __restrict__ w0,
    const float* __restrict__ w1, const float* __restrict__ w2,
    const float* __restrict__ w3,
    unsigned short* __restrict__ xb, unsigned short* __restrict__ wb) {
  const int T4 = (MTOT * DM) / 4;  // 1M float4 per buffer
  int stride = gridDim.x * blockDim.x;
  for (int i = blockIdx.x * blockDim.x + threadIdx.x; i < 2 * T4; i += stride) {
    const float* src; unsigned short* dst;
    if (i < T4) { src = x + (size_t)i * 4; dst = xb + (size_t)i * 4; }
    else {
      int flat = (i - T4) * 4;
      int sel = flat >> 20;
      int off = flat & ((1 << 20) - 1);
      const float* w = (sel == 0) ? w0 : (sel == 1) ? w1 : (sel == 2) ? w2 : w3;
      src = w + off; dst = wb + flat;
    }
    float4 v = *(const float4*)src;
    ushort4 o; o.x = f2bf(v.x); o.y = f2bf(v.y); o.z = f2bf(v.z); o.w = f2bf(v.w);
    *(ushort4*)dst = o;
  }
}

// ---------------- K1: fused projection GEMM [4096,1024]x[4096,1024]^T -------
// V blocks (which==3) transpose their 128x128 output tile through the staging
// LDS (XOR-swizzled) and write vt[bh][d][s] directly -> k_vt eliminated.
__global__ __launch_bounds__(256) void k_proj(
    const unsigned short* __restrict__ xb, const unsigned short* __restrict__ wb,
    const float* __restrict__ bbd, const float* __restrict__ bq,
    const float* __restrict__ bk, const float* __restrict__ bv,
    const float* __restrict__ radial,
    float* __restrict__ outbd,
    unsigned short* __restrict__ qb, unsigned short* __restrict__ kb,
    unsigned short* __restrict__ vt) {
  __shared__ unsigned short lsbuf[2 * 128 * 64];   // lsA | lsB, 32 KB
  unsigned short* lsA = lsbuf;
  unsigned short* lsB = lsbuf + 128 * 64;
  const int tid = threadIdx.x;
  const int wave = tid >> 6, lane = tid & 63;
  const int wr = wave >> 1, wc = wave & 1;   // 2x2 wave grid, 64x64 per wave
  // bijective XCD swizzle: 1024 blocks % 8 == 0
  const int lin = blockIdx.y * gridDim.x + blockIdx.x;
  const int swz = (lin & 7) * 128 + (lin >> 3);
  const int m0 = (swz >> 5) * 128, n0 = (swz & 31) * 128;
  const int ro = lane & 15, gg = lane >> 4;
  const int srow = lane >> 3;        // 0..7 within an 8-row chunk
  const int scol = (lane & 7) * 8;   // bf16 col within 64
  f32x4 acc[4][4] = {};
  for (int kt = 0; kt < DM / 64; ++kt) {
    __syncthreads();
    #pragma unroll
    for (int i = 0; i < 4; ++i) {
      int c = wave * 4 + i;          // chunk 0..15, 8 rows each
      const unsigned short* ga = xb + (size_t)(m0 + c * 8 + srow) * DM + kt * 64 + scol;
      gload_lds16(ga, (void*)(lsA + c * 512));
      const unsigned short* gb = wb + (size_t)(n0 + c * 8 + srow) * DM + kt * 64 + scol;
      gload_lds16(gb, (void*)(lsB + c * 512));
    }
    __syncthreads();
    #pragma unroll
    for (int ks = 0; ks < 2; ++ks) {
      short8 a[4], b[4];
      int ko = ks * 32 + gg * 8;
      #pragma unroll
      for (int r = 0; r < 4; ++r)
        a[r] = *(const short8*)&lsA[(wr * 64 + r * 16 + ro) * 64 + ko];
      #pragma unroll
      for (int c = 0; c < 4; ++c)
        b[c] = *(const short8*)&lsB[(wc * 64 + c * 16 + ro) * 64 + ko];
      #pragma unroll
      for (int r = 0; r < 4; ++r)
        #pragma unroll
        for (int c = 0; c < 4; ++c)
          acc[r][c] = MFMA(a[r], b[c], acc[r][c]);
    }
  }
  const int which = n0 >> 10;  // uniform per block
  if (which == 3) {
    // ---- V: transpose 128x128 tile via LDS, write vt[bh][d][s] ----
    __syncthreads();  // all MFMA ds-reads done before LDS reuse
    #pragma unroll
    for (int r = 0; r < 4; ++r) {
      const int rl0 = wr * 64 + r * 16 + gg * 4;   // row (s) within tile
      const int slot = rl0 >> 3;
      #pragma unroll
      for (int c = 0; c < 4; ++c) {
        const int cl = wc * 64 + c * 16 + ro;      // col (d) within tile
        const int nn = (n0 & 1023) + cl;
        ushort4 p;
        p.x = f2bf(acc[r][c][0] + bv[nn]);
        p.y = f2bf(acc[r][c][1] + bv[nn]);
        p.z = f2bf(acc[r][c][2] + bv[nn]);
        p.w = f2bf(acc[r][c][3] + bv[nn]);
        // row cl (256B), 16B slots XOR-swizzled by cl&15; 8B half by rl0&4
        const int byt = cl * 256 + (((slot ^ (cl & 15)) << 4) | ((rl0 & 4) << 1));
        *(ushort4*)((char*)lsbuf + byt) = p;
      }
    }
    __syncthreads();
    const int cl2 = tid & 127, seg = tid >> 7;
    const int nn2 = (n0 & 1023) + cl2;
    const int h2 = nn2 >> 6, d2 = nn2 & 63;
    const int b22 = m0 >> 11;
    unsigned short* vout =
        vt + ((size_t)(b22 * NH + h2) * HD + d2) * SS + (m0 & 2047);
    #pragma unroll
    for (int i = 0; i < 8; ++i) {
      const int slot2 = seg * 8 + i;
      short8 val = *(const short8*)((char*)lsbuf + cl2 * 256 +
                                    ((slot2 ^ (cl2 & 15)) << 4));
      *(short8*)(vout + slot2 * 8) = val;
    }
  } else {
    #pragma unroll
    for (int r = 0; r < 4; ++r) {
      const int mbase = m0 + wr * 64 + r * 16 + gg * 4;
      #pragma unroll
      for (int c = 0; c < 4; ++c) {
        const int n = n0 + wc * 64 + c * 16 + ro;
        const int nn = n & 1023;
        #pragma unroll
        for (int j = 0; j < 4; ++j) {
          const int m = mbase + j;
          float v = acc[r][c][j];
          if (which == 0) {
            outbd[(size_t)m * DM + nn] = v + bbd[nn];
          } else {
            const int h = nn >> 6, d = nn & 63;
            const int b2 = m >> 11, s = m & 2047;
            const size_t o = (((size_t)(b2 * NH + h)) * SS + s) * HD + d;
            if (which == 1) {
              float sg = 1.f / (1.f + __expf(-radial[h]));
              qb[o] = f2bf((v + bq[nn]) * sg);
            } else {
              kb[o] = f2bf(v + bk[nn]);
            }
          }
        }
      }
    }
  }
}

// ---------------- K2: fused scores + tropical softmax + attn write + PV -----
// Exact r10 structure (best: 275.8us). Block: 64 q-rows of one (b,h), 4
// waves. Q in registers. K/V^T double-buffered via global_load_lds with
// pre-swizzled sources (T2/G21). Pass 2: counted vmcnt(4) + raw s_barrier,
// batched back-to-back nt stores.
__global__ __launch_bounds__(256) void k_attn_pv(
    const unsigned short* __restrict__ qb, const unsigned short* __restrict__ kb,
    const unsigned short* __restrict__ vt, const float* __restrict__ tsc,
    float* __restrict__ attn, float* __restrict__ out) {
  __shared__ unsigned short lk[2][64 * 64];                  // 16 KB
  __shared__ unsigned short lv[2][64 * 64];                  // 16 KB
  __shared__ __align__(16) unsigned short pt[4][16 * 64];    // 8 KB
  const int bh = blockIdx.y, qt = blockIdx.x;
  const int tid = threadIdx.x, wave = tid >> 6, lane = tid & 63;
  const int ro = lane & 15, gg = lane >> 4;

  const unsigned short* kb_bh = kb + (size_t)bh * SS * HD;
  const unsigned short* vt_bh = vt + (size_t)bh * HD * SS;

  // staging geometry: thread stages 16B slots (wave*2+i)*64+lane, i=0,1
  int sr0, sc0, sr1, sc1;
  {
    int s0 = (wave * 2 + 0) * 64 + lane;
    int s1 = (wave * 2 + 1) * 64 + lane;
    sr0 = s0 >> 3; sc0 = (s0 & 7) ^ (sr0 & 7);
    sr1 = s1 >> 3; sc1 = (s1 & 7) ^ (sr1 & 7);
  }

#define STAGE_K(buf, kt) do { \
    const unsigned short* g = kb_bh + (size_t)(kt) * 64 * HD; \
    gload_lds16(g + sr0 * 64 + sc0 * 8, (void*)(lk[buf] + (wave * 2 + 0) * 512)); \
    gload_lds16(g + sr1 * 64 + sc1 * 8, (void*)(lk[buf] + (wave * 2 + 1) * 512)); \
  } while (0)
#define STAGE_V(buf, kt) do { \
    const unsigned short* g = vt_bh + (size_t)(kt) * 64; \
    gload_lds16(g + (size_t)sr0 * SS + sc0 * 8, (void*)(lv[buf] + (wave * 2 + 0) * 512)); \
    gload_lds16(g + (size_t)sr1 * SS + sc1 * 8, (void*)(lv[buf] + (wave * 2 + 1) * 512)); \
  } while (0)

  STAGE_K(0, 0);

  // Q straight to registers (one row per lane-group slot, 2x16B)
  const unsigned short* qrow =
      qb + ((size_t)bh * SS + qt * 64 + wave * 16 + ro) * HD;
  short8 aq0 = *(const short8*)(qrow + gg * 8);
  short8 aq1 = *(const short8*)(qrow + 32 + gg * 8);
  const float fac = tsc[0] * 0.125f;  // tropical_scale / sqrt(64)

  __syncthreads();  // drains K(0) stage + Q loads

  // ---- pass 1: row sums of exp(s*fac) ----
  float psum = 0.f;
  int cur = 0;
  for (int ct = 0; ct < 32; ++ct) {
    if (ct < 31) STAGE_K(cur ^ 1, ct + 1);
    const unsigned short* kbuf = lk[cur];
    #pragma unroll
    for (int sub = 0; sub < 4; ++sub) {
      const int rr = sub * 16 + ro;
      const unsigned short* kr = kbuf + rr * 64;
      short8 b0 = *(const short8*)&kr[(gg ^ (rr & 7)) * 8];
      short8 b1 = *(const short8*)&kr[((4 + gg) ^ (rr & 7)) * 8];
      f32x4 sf = {};
      sf = MFMA(b0, aq0, sf);   // lane: q=ro, k = ct*64+sub*16+gg*4+reg
      sf = MFMA(b1, aq1, sf);
      psum += __expf(sf[0] * fac) + __expf(sf[1] * fac)
            + __expf(sf[2] * fac) + __expf(sf[3] * fac);
    }
    __syncthreads();
    cur ^= 1;
  }
  STAGE_K(0, 0);
  STAGE_V(0, 0);
  psum += __shfl_xor(psum, 16);
  psum += __shfl_xor(psum, 32);
  const float rsum = 1.f / (psum + 1e-8f);
  __syncthreads();  // drains stage(0) -> buf0 ready

  // ---- pass 2: recompute, batched nt attn stores, PV ----
  float* ab = attn + ((size_t)bh * SS + qt * 64 + wave * 16 + ro) * SS;
  unsigned short* pw = &pt[wave][0];
  f32x4 acc[4] = {};
  cur = 0;
  for (int ct = 0; ct < 32; ++ct) {
    asm volatile("s_waitcnt vmcnt(4)" ::: "memory");
    __builtin_amdgcn_s_barrier();
    if (ct < 31) { STAGE_K(cur ^ 1, ct + 1); STAGE_V(cur ^ 1, ct + 1); }
    const unsigned short* kbuf = lk[cur];
    const unsigned short* vbuf = lv[cur];
    f32x4 st[4];
    #pragma unroll
    for (int sub = 0; sub < 4; ++sub) {
      const int rr = sub * 16 + ro;
      const unsigned short* kr = kbuf + rr * 64;
      short8 b0 = *(const short8*)&kr[(gg ^ (rr & 7)) * 8];
      short8 b1 = *(const short8*)&kr[((4 + gg) ^ (rr & 7)) * 8];
      f32x4 sf = {};
      sf = MFMA(b0, aq0, sf);
      sf = MFMA(b1, aq1, sf);
      st[sub][0] = __expf(sf[0] * fac) * rsum;
      st[sub][1] = __expf(sf[1] * fac) * rsum;
      st[sub][2] = __expf(sf[2] * fac) * rsum;
      st[sub][3] = __expf(sf[3] * fac) * rsum;
    }
    #pragma unroll
    for (int sub = 0; sub < 4; ++sub)
      __builtin_nontemporal_store(st[sub],
          (f32x4*)(ab + (ct * 4 + sub) * 16 + gg * 4));
    #pragma unroll
    for (int sub = 0; sub < 4; ++sub) {
      unsigned w0, w1;
      asm("v_cvt_pk_bf16_f32 %0, %1, %2" : "=v"(w0) : "v"(st[sub][0]), "v"(st[sub][1]));
      asm("v_cvt_pk_bf16_f32 %0, %1, %2" : "=v"(w1) : "v"(st[sub][2]), "v"(st[sub][3]));
      const int slot = (sub * 2 + (gg >> 1)) ^ (ro & 7);
      *(uint2*)((char*)pw + ro * 128 + slot * 16 + (gg & 1) * 8) = make_uint2(w0, w1);
    }
    #pragma unroll
    for (int ks = 0; ks < 2; ++ks) {
      const int pslot = (ks * 4 + gg) ^ (ro & 7);
      short8 pa = *(const short8*)((const char*)pw + ro * 128 + pslot * 16);
      #pragma unroll
      for (int dc = 0; dc < 4; ++dc) {
        const int rr = dc * 16 + ro;
        const int cc = (ks * 4 + gg) ^ (rr & 7);
        short8 bvf = *(const short8*)&vbuf[rr * 64 + cc * 8];
        acc[dc] = MFMA(pa, bvf, acc[dc]);
      }
    }
    cur ^= 1;
  }

  // epilogue: out += PV (boundary already written by k_proj)
  const int b2 = bh >> 4, h = bh & 15;
  const int s0 = qt * 64 + wave * 16 + gg * 4;
  #pragma unroll
  for (int dc = 0; dc < 4; ++dc)
    #pragma unroll
    for (int j = 0; j < 4; ++j) {
      size_t o = ((size_t)b2 * SS + s0 + j) * DM + h * HD + dc * 16 + ro;
      out[o] += acc[dc][j];
    }
#undef STAGE_K
#undef STAGE_V
}

extern "C" void kernel_launch(void* const* d_in, const int* in_sizes, int n_in,
                              void* d_out, int out_size, void* d_ws, size_t ws_size,
                              hipStream_t stream) {
  (void)in_sizes; (void)n_in; (void)out_size; (void)ws_size;
  const float* x   = (const float*)d_in[0];
  const float* Wb  = (const float*)d_in[1];
  const float* bb  = (const float*)d_in[2];
  const float* Wq  = (const float*)d_in[3];
  const float* bq  = (const float*)d_in[4];
  const float* Wk  = (const float*)d_in[5];
  const float* bk  = (const float*)d_in[6];
  const float* Wv  = (const float*)d_in[7];
  const float* bv  = (const float*)d_in[8];
  const float* rad = (const float*)d_in[9];
  const float* tsc = (const float*)d_in[10];

  float* out  = (float*)d_out;
  float* attn = out + (size_t)MTOT * DM;  // second output, also early scratch

  // ws: qb(8MB) kb(8MB) vt(8MB)
  unsigned short* qb = (unsigned short*)d_ws;
  unsigned short* kb = qb + (size_t)4 * 1024 * 1024;
  unsigned short* vt = kb + (size_t)4 * 1024 * 1024;

  // scratch carved from the attn output region (overwritten later by k_attn_pv)
  unsigned short* xb = (unsigned short*)attn;
  unsigned short* wb = xb + (size_t)4 * 1024 * 1024;

  k_convert<<<2048, 256, 0, stream>>>(x, Wb, Wq, Wk, Wv, xb, wb);
  k_proj<<<dim3(32, 32), 256, 0, stream>>>(xb, wb, bb, bq, bk, bv, rad, out, qb, kb, vt);
  k_attn_pv<<<dim3(32, 32), 256, 0, stream>>>(qb, kb, vt, tsc, attn, out);
}